// Round 8
// baseline (270.820 us; speedup 1.0000x reference)
//
#include <hip/hip_runtime.h>
#include <hip/hip_bf16.h>
#include <math.h>

#define BB 4
#define SS 1024
#define DD 1024
#define NH 16
#define DKH 64

typedef __attribute__((ext_vector_type(8))) short bf16x8;   // MFMA A/B frag (4 VGPRs)
typedef __attribute__((ext_vector_type(4))) float f32x4;    // MFMA C/D frag

__device__ __forceinline__ ushort f2bf(float f) {
  __hip_bfloat16 h = __float2bfloat16(f);
  return *(ushort*)&h;
}

__device__ __forceinline__ bf16x8 pack8(float4 a, float4 b) {
  bf16x8 r;
  r[0] = (short)f2bf(a.x); r[1] = (short)f2bf(a.y);
  r[2] = (short)f2bf(a.z); r[3] = (short)f2bf(a.w);
  r[4] = (short)f2bf(b.x); r[5] = (short)f2bf(b.y);
  r[6] = (short)f2bf(b.z); r[7] = (short)f2bf(b.w);
  return r;
}

// async global -> LDS, 16 B per lane; LDS dest = wave-uniform base + lane*16
__device__ __forceinline__ void async16(const void* g, void* l) {
  __builtin_amdgcn_global_load_lds(
      (const __attribute__((address_space(1))) unsigned int*)g,
      (__attribute__((address_space(3))) unsigned int*)l, 16, 0, 0);
}

// ---------------------------------------------------------------------------
// prep_all (one dispatch; reductions first, conversions grid-stride x8 so
// each block has a latency-hiding loop instead of one-shot load/store):
//  [0,64)        wo_sum: block streams 16 contiguous Wo rows, 4 atomicAdds
//  64            bo_mean (fp32, exact, deterministic)
//  [65,577)      maskOK = all-ones test per 128x64 mask tile
//  [577,1345)    q,k,v fp32 -> dense bf16 (768 blocks x 8 chunks)
//  [1345,1537)   Wq/Wk/Wv fp32 -> dense bf16 (192 blocks x 8 chunks)
// ---------------------------------------------------------------------------
__global__ __launch_bounds__(256) void prep_all(
    const float* __restrict__ Xq, const float* __restrict__ Xk, const float* __restrict__ Xv,
    const int* __restrict__ mask,
    const float* __restrict__ Wq, const float* __restrict__ Wk, const float* __restrict__ Wv,
    const float* __restrict__ Wo, const float* __restrict__ bo,
    ushort* __restrict__ Wb, ushort* __restrict__ Ab,
    float* __restrict__ wo_sum, float* __restrict__ bo_mean,
    int* __restrict__ maskOK) {
  __shared__ int smi[4];
  const int bid = blockIdx.x;
  const int tid = threadIdx.x;

  if (bid < 64) {
    const int row0 = bid * 16;
    float4 acc = make_float4(0.f, 0.f, 0.f, 0.f);
#pragma unroll
    for (int r = 0; r < 16; ++r) {
      const float4 v = *(const float4*)(Wo + (size_t)(row0 + r) * DD + tid * 4);
      acc.x += v.x; acc.y += v.y; acc.z += v.z; acc.w += v.w;
    }
    atomicAdd(&wo_sum[tid * 4 + 0], acc.x);
    atomicAdd(&wo_sum[tid * 4 + 1], acc.y);
    atomicAdd(&wo_sum[tid * 4 + 2], acc.z);
    atomicAdd(&wo_sum[tid * 4 + 3], acc.w);
    return;
  }

  if (bid == 64) {
    if (tid < 64) {
      float s = 0.f;
      for (int i = tid; i < 1024; i += 64) s += bo[i];
#pragma unroll
      for (int off = 1; off < 64; off <<= 1) s += __shfl_xor(s, off);
      if (tid == 0) *bo_mean = s * (1.0f / 1024.0f);
    }
    return;
  }

  if (bid < 577) {
    const int m = bid - 65;            // 0..511
    const int kt = m & 15, qt = (m >> 4) & 7, b = m >> 7;
    const int row = tid >> 1, half = tid & 1;
    const int* p = mask + ((size_t)b * SS + qt * 128 + row) * SS + kt * 64 + half * 32;
    int ok = 1;
#pragma unroll
    for (int j = 0; j < 8; ++j) {
      const int4 mm = *(const int4*)(p + j * 4);
      ok &= (mm.x != 0) & (mm.y != 0) & (mm.z != 0) & (mm.w != 0);
    }
    const unsigned long long bal = __ballot(ok);
    if ((tid & 63) == 0) smi[tid >> 6] = (bal == ~0ULL) ? 1 : 0;
    __syncthreads();
    if (tid == 0) maskOK[(b * 8 + qt) * 16 + kt] = smi[0] & smi[1] & smi[2] & smi[3];
    return;
  }

  if (bid < 1345) {
    // -------- activations: grid-stride x8, dense bf16 ---------------------
    const int c0 = bid - 577;          // 0..767
#pragma unroll
    for (int it = 0; it < 8; ++it) {
      const size_t g = (size_t)(c0 + it * 768) * 2048 + (size_t)tid * 8;
      const int t = (int)(g >> 22);
      const float* base = (t == 0) ? Xq : (t == 1) ? Xk : Xv;
      const size_t off = g & 4194303;
      const float4 f0 = *(const float4*)(base + off);
      const float4 f1 = *(const float4*)(base + off + 4);
      *(bf16x8*)(Ab + g) = pack8(f0, f1);
    }
    return;
  }

  {
    // -------- weights: grid-stride x8, dense bf16 -------------------------
    const int c0 = bid - 1345;         // 0..191
#pragma unroll
    for (int it = 0; it < 8; ++it) {
      const size_t g = (size_t)(c0 + it * 192) * 2048 + (size_t)tid * 8;
      const int t = (int)(g >> 20);
      const float* W = (t == 0) ? Wq : (t == 1) ? Wk : Wv;
      const size_t off = g & 1048575;
      const float4 f0 = *(const float4*)(W + off);
      const float4 f1 = *(const float4*)(W + off + 4);
      *(bf16x8*)(Wb + g) = pack8(f0, f1);
    }
  }
}

// ---------------------------------------------------------------------------
// bf16 MFMA GEMM, double-buffered BK=32 K-loop (ONE barrier per slab):
// stage slab k+1 into buf^1 right after the barrier, compute slab k from buf
// -> global->LDS latency overlaps the 16 MFMAs instead of draining at a
// second barrier. 128x128 tile, global_load_lds w16, XOR swizzle
// (chunk ^ row&3) keeps b128 frag reads at the conflict-free minimum.
// Grid (m=32,n=8,z=3) for per-XCD A-tile L2 residency.
// ---------------------------------------------------------------------------
__global__ __launch_bounds__(256) void gemm_qkv_bf16(
    const ushort* __restrict__ Ab, const ushort* __restrict__ Wb,
    const float* __restrict__ bq, const float* __restrict__ bk, const float* __restrict__ bv,
    ushort* __restrict__ QKVb) {
  const int z = blockIdx.z;
  const char* A = (const char*)(Ab + (size_t)z * 4194304);
  const char* W = (const char*)(Wb + (size_t)z * 1048576);
  const float* bias = (z == 0) ? bq : (z == 1) ? bk : bv;
  ushort* Cz = QKVb + (size_t)z * 4194304;
  const float sc = (z == 0) ? 0.125f : 1.0f;

  __shared__ ushort As[2][4096];  // 128 rows x 32 elts per buffer (8 KB each)
  __shared__ ushort Ws[2][4096];

  const int tid = threadIdx.x;
  const int lane = tid & 63, w = tid >> 6;
  const int quad = lane >> 4, l15 = lane & 15;
  const int wn = w & 1, wm = w >> 1;
  const int m0 = blockIdx.x * 128, n0 = blockIdx.y * 128;

  // staging: 16 rows per async16; lane covers row r4 = lane>>2, global chunk
  // gc = (lane&3) ^ (r4&3)  (XOR swizzle; reader applies quad ^ (l15&3))
  const int r4 = lane >> 2;
  const int gc = (lane & 3) ^ (r4 & 3);
  const int rc = quad ^ (l15 & 3);  // reader's swizzled chunk

  f32x4 acc[4][4];
  const f32x4 z4 = {0.f, 0.f, 0.f, 0.f};
#pragma unroll
  for (int mt = 0; mt < 4; ++mt)
#pragma unroll
    for (int nt = 0; nt < 4; ++nt) acc[mt][nt] = z4;

  auto stage = [&](int k0, int buf) {
#pragma unroll
    for (int j = 0; j < 2; ++j) {
      const int grp = w * 2 + j;            // 8 groups of 16 rows
      const int row = grp * 16 + r4;
      async16(A + ((size_t)(m0 + row) * DD + k0 + gc * 8) * 2, &As[buf][grp * 512]);
      async16(W + ((size_t)(n0 + row) * DD + k0 + gc * 8) * 2, &Ws[buf][grp * 512]);
    }
  };

  stage(0, 0);
  for (int k0 = 0; k0 < DD; k0 += 32) {
    const int buf = (k0 >> 5) & 1;
    __syncthreads();  // drains this buf's asyncs; joins prior compute on buf^1
    if (k0 + 32 < DD) stage(k0 + 32, buf ^ 1);  // overlaps compute below
    bf16x8 wf[4], af[4];
#pragma unroll
    for (int nt = 0; nt < 4; ++nt)
      wf[nt] = *(const bf16x8*)&Ws[buf][(wn * 64 + nt * 16 + l15) * 32 + rc * 8];
#pragma unroll
    for (int mt = 0; mt < 4; ++mt)
      af[mt] = *(const bf16x8*)&As[buf][(wm * 64 + mt * 16 + l15) * 32 + rc * 8];
#pragma unroll
    for (int mt = 0; mt < 4; ++mt)
#pragma unroll
      for (int nt = 0; nt < 4; ++nt)
        acc[mt][nt] = __builtin_amdgcn_mfma_f32_16x16x32_bf16(wf[nt], af[mt], acc[mt][nt], 0, 0, 0);
  }

  // epilogue: bias + scale, lane holds 4 consecutive C-cols (operand swap)
#pragma unroll
  for (int nt = 0; nt < 4; ++nt) {
    const float4 b4 = *(const float4*)(bias + n0 + wn * 64 + nt * 16 + quad * 4);
#pragma unroll
    for (int mt = 0; mt < 4; ++mt) {
      const f32x4 v = acc[mt][nt];
      ushort4 pk;
      pk.x = f2bf((v[0] + b4.x) * sc);
      pk.y = f2bf((v[1] + b4.y) * sc);
      pk.z = f2bf((v[2] + b4.z) * sc);
      pk.w = f2bf((v[3] + b4.w) * sc);
      *(ushort4*)&Cz[(size_t)(m0 + wm * 64 + mt * 16 + l15) * DD + n0 + wn * 64 + nt * 16 + quad * 4] = pk;
    }
  }
}

// ---------------------------------------------------------------------------
// MFMA flash attention, 64-q blocks (grid 1024 = 4 blocks/CU, 2x round-7
// concurrency; wave = 16 q-rows, ~40 fewer live VGPRs). Two-barrier LDS
// K-loop, K frags from global before V staging, max-free softmax,
// grid (h=16, qblk=16, b=4) keeps per-XCD K/V L2 residency.
// ---------------------------------------------------------------------------
__global__ __launch_bounds__(256) void flash_mfma(
    const ushort* __restrict__ QKVb, const int* __restrict__ mask,
    const int* __restrict__ maskOK, float* __restrict__ X) {
  __shared__ ushort Vt[64 * 72];   // V^T [d][key], padded
  __shared__ ushort Ps[64 * 72];   // P^T [q_local][key], padded

  const ushort* Qb = QKVb;
  const ushort* Kb = QKVb + 4194304;
  const ushort* Vb = QKVb + 8388608;

  const int tid = threadIdx.x;
  const int lane = tid & 63, w = tid >> 6;
  const int quad = lane >> 4, l15 = lane & 15;
  const int h = blockIdx.x, qblk = blockIdx.y, b = blockIdx.z;
  const int qbase = qblk * 64 + w * 16;  // this wave's 16 q-rows

  // Q fragments (B-operand), register-resident for all 16 K-tiles
  bf16x8 qf[2];
#pragma unroll
  for (int ks = 0; ks < 2; ++ks)
    qf[ks] = *(const bf16x8*)(Qb + (size_t)(b * SS + qbase + l15) * DD +
                              h * DKH + ks * 32 + quad * 8);

  f32x4 o[4];
  const f32x4 z4 = {0.f, 0.f, 0.f, 0.f};
#pragma unroll
  for (int dt = 0; dt < 4; ++dt) o[dt] = z4;
  float l_run = 0.f;

  const int vp = tid & 31;   // key pair index
  const int vdc = tid >> 5;  // d-chunk (8 dims)
  const ushort* Vg = Vb + (size_t)(b * SS) * DD + h * DKH + vdc * 8;
  const ushort* Kg = Kb + (size_t)(b * SS) * DD + h * DKH;
  uint* VtU = (uint*)Vt;
  const int* Mb = mask + (size_t)b * SS * SS;

  for (int kt = 0; kt < 16; ++kt) {
    const int k064 = kt * 64;
    __syncthreads();  // prior iteration's Vt reads complete

    // K fragments for THIS tile (global, L1/L2-hot) — issued first so the
    // vmcnt latency overlaps the V pack + LDS writes below
    bf16x8 kf[4][2];
#pragma unroll
    for (int mt = 0; mt < 4; ++mt)
#pragma unroll
      for (int ks = 0; ks < 2; ++ks)
        kf[mt][ks] = *(const bf16x8*)(Kg + (size_t)(k064 + mt * 16 + l15) * DD +
                                      ks * 32 + quad * 8);

    // stage V transposed: pack (key 2p, 2p+1) pairs -> b32 writes
    union { uint4 u; ushort s[8]; } v0, v1;
    v0.u = *(const uint4*)(Vg + (size_t)(k064 + 2 * vp) * DD);
    v1.u = *(const uint4*)(Vg + (size_t)(k064 + 2 * vp + 1) * DD);
#pragma unroll
    for (int j = 0; j < 8; ++j)
      VtU[(vdc * 8 + j) * 36 + vp] = (uint)v0.s[j] | ((uint)v1.s[j] << 16);
    __syncthreads();  // Vt visible

    // S^T tiles: rows = keys (quad*4+reg), col = this wave's q (lane&15)
    f32x4 s[4];
#pragma unroll
    for (int mt = 0; mt < 4; ++mt) {
      f32x4 a = z4;
      a = __builtin_amdgcn_mfma_f32_16x16x32_bf16(kf[mt][0], qf[0], a, 0, 0, 0);
      a = __builtin_amdgcn_mfma_f32_16x16x32_bf16(kf[mt][1], qf[1], a, 0, 0, 0);
      s[mt] = a;
    }

    // mask (fast path: whole 128x64 tile all-ones -> skip)
    const int ok = maskOK[(b * 8 + (qblk >> 1)) * 16 + kt];
    if (!ok) {
#pragma unroll
      for (int mt = 0; mt < 4; ++mt)
#pragma unroll
        for (int reg = 0; reg < 4; ++reg) {
          const int q = qbase + l15;
          const int key = k064 + mt * 16 + quad * 4 + reg;
          if (Mb[(size_t)q * SS + key] == 0) s[mt][reg] = -1e9f;
        }
    }

    // max-free softmax: p = exp(s), per-lane partial l, no rescale
    float rs = 0.f;
#pragma unroll
    for (int mt = 0; mt < 4; ++mt) {
#pragma unroll
      for (int reg = 0; reg < 4; ++reg) {
        const float p = __expf(s[mt][reg]);
        s[mt][reg] = p;
        rs += p;
      }
    }
    l_run += rs;
    // write P^T (wave-local rows -> no barrier; compiler orders lgkm)
#pragma unroll
    for (int mt = 0; mt < 4; ++mt) {
      ushort4 pk;
      pk.x = f2bf(s[mt][0]);
      pk.y = f2bf(s[mt][1]);
      pk.z = f2bf(s[mt][2]);
      pk.w = f2bf(s[mt][3]);
      *(ushort4*)&Ps[(w * 16 + l15) * 72 + mt * 16 + quad * 4] = pk;
    }

    // O^T += V^T · P^T
    bf16x8 pf[2];
#pragma unroll
    for (int ks = 0; ks < 2; ++ks)
      pf[ks] = *(const bf16x8*)&Ps[(w * 16 + l15) * 72 + ks * 32 + quad * 8];
#pragma unroll
    for (int dt = 0; dt < 4; ++dt) {
      bf16x8 vf0 = *(const bf16x8*)&Vt[(dt * 16 + l15) * 72 + quad * 8];
      bf16x8 vf1 = *(const bf16x8*)&Vt[(dt * 16 + l15) * 72 + 32 + quad * 8];
      o[dt] = __builtin_amdgcn_mfma_f32_16x16x32_bf16(vf0, pf[0], o[dt], 0, 0, 0);
      o[dt] = __builtin_amdgcn_mfma_f32_16x16x32_bf16(vf1, pf[1], o[dt], 0, 0, 0);
    }
  }

  // reduce l across quads (lanes sharing the same q), normalize, store
  {
    float l = l_run;
    l += __shfl_xor(l, 16);
    l += __shfl_xor(l, 32);
    const float inv = 1.0f / l;
#pragma unroll
    for (int dt = 0; dt < 4; ++dt) {
      const f32x4 ov = o[dt] * inv;
      *(f32x4*)(X + (size_t)(b * SS + qbase + l15) * DD +
                h * DKH + dt * 16 + quad * 4) = ov;
    }
  }
}

// ---------------------------------------------------------------------------
// Epilogue: 4 rows per block (grid 1024), single barrier, wo slice in regs.
// xt = threshold(x,0.2); x1 = dot(xt,wo_sum)/1024 + bo_mean; out = xt + x1
// ---------------------------------------------------------------------------
__global__ __launch_bounds__(256) void epilogue_kernel(float* __restrict__ X,
                                                       const float* __restrict__ wo_sum,
                                                       const float* __restrict__ bo_mean) {
  __shared__ float red[4][4];
  const int tid = threadIdx.x;
  const float4 wv = *(const float4*)(wo_sum + tid * 4);
  const float bm = *bo_mean;
  float4 xt[4];
#pragma unroll
  for (int r = 0; r < 4; ++r) {
    const int row = blockIdx.x * 4 + r;
    const float4 x = *(const float4*)(X + (size_t)row * DD + tid * 4);
    xt[r].x = (x.x > 0.2f) ? x.x : 0.f;
    xt[r].y = (x.y > 0.2f) ? x.y : 0.f;
    xt[r].z = (x.z > 0.2f) ? x.z : 0.f;
    xt[r].w = (x.w > 0.2f) ? x.w : 0.f;
    float part = xt[r].x * wv.x + xt[r].y * wv.y + xt[r].z * wv.z + xt[r].w * wv.w;
#pragma unroll
    for (int off = 1; off < 64; off <<= 1) part += __shfl_xor(part, off);
    if ((tid & 63) == 0) red[r][tid >> 6] = part;
  }
  __syncthreads();
#pragma unroll
  for (int r = 0; r < 4; ++r) {
    const int row = blockIdx.x * 4 + r;
    const float x1 = ((red[r][0] + red[r][1]) + (red[r][2] + red[r][3])) * (1.0f / 1024.0f) + bm;
    const float4 o = make_float4(xt[r].x + x1, xt[r].y + x1, xt[r].z + x1, xt[r].w + x1);
    *(float4*)(X + (size_t)row * DD + tid * 4) = o;
  }
}

// ---------------------------------------------------------------------------
extern "C" void kernel_launch(void* const* d_in, const int* in_sizes, int n_in,
                              void* d_out, int out_size, void* d_ws, size_t ws_size,
                              hipStream_t stream) {
  const float* Xq = (const float*)d_in[0];
  const float* Xk = (const float*)d_in[1];
  const float* Xv = (const float*)d_in[2];
  const int* mask = (const int*)d_in[3];
  const float* Wq = (const float*)d_in[4];
  const float* bq = (const float*)d_in[5];
  const float* Wk = (const float*)d_in[6];
  const float* bk = (const float*)d_in[7];
  const float* Wv = (const float*)d_in[8];
  const float* bv = (const float*)d_in[9];
  const float* Wo = (const float*)d_in[10];
  const float* bo = (const float*)d_in[11];

  // workspace (~54 MB): Wb 6 MB + Ab 24 MB + QKVb 24 MB + tails
  ushort* Wb = (ushort*)d_ws;                     // 3 x 1048576 bf16
  ushort* Ab = Wb + (size_t)3 * 1048576;          // 3 x 4194304 bf16 (dense q,k,v)
  ushort* QKVb = Ab + (size_t)3 * 4194304;        // 3 x 4194304 bf16
  float* wo_sum = (float*)(QKVb + (size_t)3 * 4194304);
  float* bo_mean = wo_sum + 1024;
  int* maskOK = (int*)(bo_mean + 1);              // 512 ints
  float* X = (float*)d_out;

  hipMemsetAsync(wo_sum, 0, 1024 * sizeof(float), stream);

  prep_all<<<1537, 256, 0, stream>>>(Xq, Xk, Xv, mask, Wq, Wk, Wv, Wo, bo,
                                     Wb, Ab, wo_sum, bo_mean, maskOK);

  gemm_qkv_bf16<<<dim3(32, 8, 3), 256, 0, stream>>>(Ab, Wb, bq, bk, bv, QKVb);

  flash_mfma<<<dim3(16, 16, 4), 256, 0, stream>>>(QKVb, mask, maskOK, X);

  epilogue_kernel<<<1024, 256, 0, stream>>>(X, wo_sum, bo_mean);
}

// Round 9
// 233.758 us; speedup vs baseline: 1.1586x; 1.1586x over previous
//
#include <hip/hip_runtime.h>
#include <hip/hip_bf16.h>
#include <math.h>

#define BB 4
#define SS 1024
#define DD 1024
#define NH 16
#define DKH 64

typedef __attribute__((ext_vector_type(8))) short bf16x8;   // MFMA A/B frag (4 VGPRs)
typedef __attribute__((ext_vector_type(4))) float f32x4;    // MFMA C/D frag

__device__ __forceinline__ ushort f2bf(float f) {
  __hip_bfloat16 h = __float2bfloat16(f);
  return *(ushort*)&h;
}

__device__ __forceinline__ bf16x8 pack8(float4 a, float4 b) {
  bf16x8 r;
  r[0] = (short)f2bf(a.x); r[1] = (short)f2bf(a.y);
  r[2] = (short)f2bf(a.z); r[3] = (short)f2bf(a.w);
  r[4] = (short)f2bf(b.x); r[5] = (short)f2bf(b.y);
  r[6] = (short)f2bf(b.z); r[7] = (short)f2bf(b.w);
  return r;
}

// async global -> LDS, 16 B per lane; LDS dest = wave-uniform base + lane*16
__device__ __forceinline__ void async16(const void* g, void* l) {
  __builtin_amdgcn_global_load_lds(
      (const __attribute__((address_space(1))) unsigned int*)g,
      (__attribute__((address_space(3))) unsigned int*)l, 16, 0, 0);
}

// ---------------------------------------------------------------------------
// prep_all (round-8 layout: reductions first, conversions grid-stride x8):
//  [0,64)        wo_sum: block streams 16 contiguous Wo rows, 4 atomicAdds
//  64            bo_mean (fp32, exact, deterministic)
//  [65,577)      maskOK = all-ones test per 128x64 mask tile
//  [577,1345)    q,k,v fp32 -> dense bf16 (768 blocks x 8 chunks)
//  [1345,1537)   Wq/Wk/Wv fp32 -> dense bf16 (192 blocks x 8 chunks)
// ---------------------------------------------------------------------------
__global__ __launch_bounds__(256) void prep_all(
    const float* __restrict__ Xq, const float* __restrict__ Xk, const float* __restrict__ Xv,
    const int* __restrict__ mask,
    const float* __restrict__ Wq, const float* __restrict__ Wk, const float* __restrict__ Wv,
    const float* __restrict__ Wo, const float* __restrict__ bo,
    ushort* __restrict__ Wb, ushort* __restrict__ Ab,
    float* __restrict__ wo_sum, float* __restrict__ bo_mean,
    int* __restrict__ maskOK) {
  __shared__ int smi[4];
  const int bid = blockIdx.x;
  const int tid = threadIdx.x;

  if (bid < 64) {
    const int row0 = bid * 16;
    float4 acc = make_float4(0.f, 0.f, 0.f, 0.f);
#pragma unroll
    for (int r = 0; r < 16; ++r) {
      const float4 v = *(const float4*)(Wo + (size_t)(row0 + r) * DD + tid * 4);
      acc.x += v.x; acc.y += v.y; acc.z += v.z; acc.w += v.w;
    }
    atomicAdd(&wo_sum[tid * 4 + 0], acc.x);
    atomicAdd(&wo_sum[tid * 4 + 1], acc.y);
    atomicAdd(&wo_sum[tid * 4 + 2], acc.z);
    atomicAdd(&wo_sum[tid * 4 + 3], acc.w);
    return;
  }

  if (bid == 64) {
    if (tid < 64) {
      float s = 0.f;
      for (int i = tid; i < 1024; i += 64) s += bo[i];
#pragma unroll
      for (int off = 1; off < 64; off <<= 1) s += __shfl_xor(s, off);
      if (tid == 0) *bo_mean = s * (1.0f / 1024.0f);
    }
    return;
  }

  if (bid < 577) {
    const int m = bid - 65;            // 0..511
    const int kt = m & 15, qt = (m >> 4) & 7, b = m >> 7;
    const int row = tid >> 1, half = tid & 1;
    const int* p = mask + ((size_t)b * SS + qt * 128 + row) * SS + kt * 64 + half * 32;
    int ok = 1;
#pragma unroll
    for (int j = 0; j < 8; ++j) {
      const int4 mm = *(const int4*)(p + j * 4);
      ok &= (mm.x != 0) & (mm.y != 0) & (mm.z != 0) & (mm.w != 0);
    }
    const unsigned long long bal = __ballot(ok);
    if ((tid & 63) == 0) smi[tid >> 6] = (bal == ~0ULL) ? 1 : 0;
    __syncthreads();
    if (tid == 0) maskOK[(b * 8 + qt) * 16 + kt] = smi[0] & smi[1] & smi[2] & smi[3];
    return;
  }

  if (bid < 1345) {
    const int c0 = bid - 577;          // 0..767
#pragma unroll
    for (int it = 0; it < 8; ++it) {
      const size_t g = (size_t)(c0 + it * 768) * 2048 + (size_t)tid * 8;
      const int t = (int)(g >> 22);
      const float* base = (t == 0) ? Xq : (t == 1) ? Xk : Xv;
      const size_t off = g & 4194303;
      const float4 f0 = *(const float4*)(base + off);
      const float4 f1 = *(const float4*)(base + off + 4);
      *(bf16x8*)(Ab + g) = pack8(f0, f1);
    }
    return;
  }

  {
    const int c0 = bid - 1345;         // 0..191
#pragma unroll
    for (int it = 0; it < 8; ++it) {
      const size_t g = (size_t)(c0 + it * 192) * 2048 + (size_t)tid * 8;
      const int t = (int)(g >> 20);
      const float* W = (t == 0) ? Wq : (t == 1) ? Wk : Wv;
      const size_t off = g & 1048575;
      const float4 f0 = *(const float4*)(W + off);
      const float4 f1 = *(const float4*)(W + off + 4);
      *(bf16x8*)(Wb + g) = pack8(f0, f1);
    }
  }
}

// ---------------------------------------------------------------------------
// bf16 MFMA GEMM, double-buffered BK=32 K-loop (round-8 structure, kept to
// read its counters this round): one barrier per slab; stage slab k+1 into
// buf^1 right after the barrier so the global->LDS latency overlaps the 16
// MFMAs. XOR swizzle (chunk ^ row&3). Grid (m=32,n=8,z=3).
// ---------------------------------------------------------------------------
__global__ __launch_bounds__(256) void gemm_qkv_bf16(
    const ushort* __restrict__ Ab, const ushort* __restrict__ Wb,
    const float* __restrict__ bq, const float* __restrict__ bk, const float* __restrict__ bv,
    ushort* __restrict__ QKVb) {
  const int z = blockIdx.z;
  const char* A = (const char*)(Ab + (size_t)z * 4194304);
  const char* W = (const char*)(Wb + (size_t)z * 1048576);
  const float* bias = (z == 0) ? bq : (z == 1) ? bk : bv;
  ushort* Cz = QKVb + (size_t)z * 4194304;
  const float sc = (z == 0) ? 0.125f : 1.0f;

  __shared__ ushort As[2][4096];  // 128 rows x 32 elts per buffer (8 KB each)
  __shared__ ushort Ws[2][4096];

  const int tid = threadIdx.x;
  const int lane = tid & 63, w = tid >> 6;
  const int quad = lane >> 4, l15 = lane & 15;
  const int wn = w & 1, wm = w >> 1;
  const int m0 = blockIdx.x * 128, n0 = blockIdx.y * 128;

  const int r4 = lane >> 2;
  const int gc = (lane & 3) ^ (r4 & 3);
  const int rc = quad ^ (l15 & 3);  // reader's swizzled chunk

  f32x4 acc[4][4];
  const f32x4 z4 = {0.f, 0.f, 0.f, 0.f};
#pragma unroll
  for (int mt = 0; mt < 4; ++mt)
#pragma unroll
    for (int nt = 0; nt < 4; ++nt) acc[mt][nt] = z4;

  auto stage = [&](int k0, int buf) {
#pragma unroll
    for (int j = 0; j < 2; ++j) {
      const int grp = w * 2 + j;            // 8 groups of 16 rows
      const int row = grp * 16 + r4;
      async16(A + ((size_t)(m0 + row) * DD + k0 + gc * 8) * 2, &As[buf][grp * 512]);
      async16(W + ((size_t)(n0 + row) * DD + k0 + gc * 8) * 2, &Ws[buf][grp * 512]);
    }
  };

  stage(0, 0);
  for (int k0 = 0; k0 < DD; k0 += 32) {
    const int buf = (k0 >> 5) & 1;
    __syncthreads();  // drains this buf's asyncs; joins prior compute on buf^1
    if (k0 + 32 < DD) stage(k0 + 32, buf ^ 1);  // overlaps compute below
    bf16x8 wf[4], af[4];
#pragma unroll
    for (int nt = 0; nt < 4; ++nt)
      wf[nt] = *(const bf16x8*)&Ws[buf][(wn * 64 + nt * 16 + l15) * 32 + rc * 8];
#pragma unroll
    for (int mt = 0; mt < 4; ++mt)
      af[mt] = *(const bf16x8*)&As[buf][(wm * 64 + mt * 16 + l15) * 32 + rc * 8];
#pragma unroll
    for (int mt = 0; mt < 4; ++mt)
#pragma unroll
      for (int nt = 0; nt < 4; ++nt)
        acc[mt][nt] = __builtin_amdgcn_mfma_f32_16x16x32_bf16(wf[nt], af[mt], acc[mt][nt], 0, 0, 0);
  }

#pragma unroll
  for (int nt = 0; nt < 4; ++nt) {
    const float4 b4 = *(const float4*)(bias + n0 + wn * 64 + nt * 16 + quad * 4);
#pragma unroll
    for (int mt = 0; mt < 4; ++mt) {
      const f32x4 v = acc[mt][nt];
      ushort4 pk;
      pk.x = f2bf((v[0] + b4.x) * sc);
      pk.y = f2bf((v[1] + b4.y) * sc);
      pk.z = f2bf((v[2] + b4.z) * sc);
      pk.w = f2bf((v[3] + b4.w) * sc);
      *(ushort4*)&Cz[(size_t)(m0 + wm * 64 + mt * 16 + l15) * DD + n0 + wn * 64 + nt * 16 + quad * 4] = pk;
    }
  }
}

// ---------------------------------------------------------------------------
// MFMA flash attention — ROUND-7 EXACT REVERT (measured 48.6 µs):
// 128-q blocks (wave = 32 q-rows), two-barrier LDS K-loop, K frags from
// global before V staging, max-free softmax, grid (h=16, qblk=8, b=4).
// Round-8's 64-q split doubled K/V staging per q-row and halved per-wave
// MFMA per barrier -> 85 µs; big tile wins here.
// ---------------------------------------------------------------------------
__global__ __launch_bounds__(256) void flash_mfma(
    const ushort* __restrict__ QKVb, const int* __restrict__ mask,
    const int* __restrict__ maskOK, float* __restrict__ X) {
  __shared__ ushort Vt[64 * 72];   // V^T [d][key], padded
  __shared__ ushort Ps[128 * 72];  // P^T [q_local][key], padded

  const ushort* Qb = QKVb;
  const ushort* Kb = QKVb + 4194304;
  const ushort* Vb = QKVb + 8388608;

  const int tid = threadIdx.x;
  const int lane = tid & 63, w = tid >> 6;
  const int quad = lane >> 4, l15 = lane & 15;
  const int h = blockIdx.x, qblk = blockIdx.y, b = blockIdx.z;
  const int qbase = qblk * 128 + w * 32;

  bf16x8 qf[2][2];
#pragma unroll
  for (int qt = 0; qt < 2; ++qt)
#pragma unroll
    for (int ks = 0; ks < 2; ++ks)
      qf[qt][ks] = *(const bf16x8*)(Qb + (size_t)(b * SS + qbase + qt * 16 + l15) * DD +
                                    h * DKH + ks * 32 + quad * 8);

  f32x4 o[4][2];
  const f32x4 z4 = {0.f, 0.f, 0.f, 0.f};
#pragma unroll
  for (int dt = 0; dt < 4; ++dt)
#pragma unroll
    for (int qt = 0; qt < 2; ++qt) o[dt][qt] = z4;
  float l_run[2] = {0.f, 0.f};

  const int vp = tid & 31;   // key pair index
  const int vdc = tid >> 5;  // d-chunk (8 dims)
  const ushort* Vg = Vb + (size_t)(b * SS) * DD + h * DKH + vdc * 8;
  const ushort* Kg = Kb + (size_t)(b * SS) * DD + h * DKH;
  uint* VtU = (uint*)Vt;
  const int* Mb = mask + (size_t)b * SS * SS;

  for (int kt = 0; kt < 16; ++kt) {
    const int k064 = kt * 64;
    __syncthreads();  // prior iteration's Vt/Ps reads complete

    bf16x8 kf[4][2];
#pragma unroll
    for (int mt = 0; mt < 4; ++mt)
#pragma unroll
      for (int ks = 0; ks < 2; ++ks)
        kf[mt][ks] = *(const bf16x8*)(Kg + (size_t)(k064 + mt * 16 + l15) * DD +
                                      ks * 32 + quad * 8);

    union { uint4 u; ushort s[8]; } v0, v1;
    v0.u = *(const uint4*)(Vg + (size_t)(k064 + 2 * vp) * DD);
    v1.u = *(const uint4*)(Vg + (size_t)(k064 + 2 * vp + 1) * DD);
#pragma unroll
    for (int j = 0; j < 8; ++j)
      VtU[(vdc * 8 + j) * 36 + vp] = (uint)v0.s[j] | ((uint)v1.s[j] << 16);
    __syncthreads();  // Vt visible

    f32x4 s[4][2];
#pragma unroll
    for (int mt = 0; mt < 4; ++mt)
#pragma unroll
      for (int qt = 0; qt < 2; ++qt) {
        f32x4 a = z4;
        a = __builtin_amdgcn_mfma_f32_16x16x32_bf16(kf[mt][0], qf[qt][0], a, 0, 0, 0);
        a = __builtin_amdgcn_mfma_f32_16x16x32_bf16(kf[mt][1], qf[qt][1], a, 0, 0, 0);
        s[mt][qt] = a;
      }

    const int ok = maskOK[(b * 8 + qblk) * 16 + kt];
    if (!ok) {
#pragma unroll
      for (int mt = 0; mt < 4; ++mt)
#pragma unroll
        for (int qt = 0; qt < 2; ++qt)
#pragma unroll
          for (int reg = 0; reg < 4; ++reg) {
            const int q = qbase + qt * 16 + l15;
            const int key = k064 + mt * 16 + quad * 4 + reg;
            if (Mb[(size_t)q * SS + key] == 0) s[mt][qt][reg] = -1e9f;
          }
    }

#pragma unroll
    for (int qt = 0; qt < 2; ++qt) {
      float rs = 0.f;
#pragma unroll
      for (int mt = 0; mt < 4; ++mt) {
#pragma unroll
        for (int reg = 0; reg < 4; ++reg) {
          const float p = __expf(s[mt][qt][reg]);
          s[mt][qt][reg] = p;
          rs += p;
        }
      }
      l_run[qt] += rs;
#pragma unroll
      for (int mt = 0; mt < 4; ++mt) {
        ushort4 pk;
        pk.x = f2bf(s[mt][qt][0]);
        pk.y = f2bf(s[mt][qt][1]);
        pk.z = f2bf(s[mt][qt][2]);
        pk.w = f2bf(s[mt][qt][3]);
        *(ushort4*)&Ps[(w * 32 + qt * 16 + l15) * 72 + mt * 16 + quad * 4] = pk;
      }
    }

    bf16x8 pf[2][2];
#pragma unroll
    for (int qt = 0; qt < 2; ++qt)
#pragma unroll
      for (int ks = 0; ks < 2; ++ks)
        pf[qt][ks] = *(const bf16x8*)&Ps[(w * 32 + qt * 16 + l15) * 72 + ks * 32 + quad * 8];
#pragma unroll
    for (int dt = 0; dt < 4; ++dt) {
      bf16x8 vf0 = *(const bf16x8*)&Vt[(dt * 16 + l15) * 72 + quad * 8];
      bf16x8 vf1 = *(const bf16x8*)&Vt[(dt * 16 + l15) * 72 + 32 + quad * 8];
#pragma unroll
      for (int qt = 0; qt < 2; ++qt) {
        o[dt][qt] = __builtin_amdgcn_mfma_f32_16x16x32_bf16(vf0, pf[qt][0], o[dt][qt], 0, 0, 0);
        o[dt][qt] = __builtin_amdgcn_mfma_f32_16x16x32_bf16(vf1, pf[qt][1], o[dt][qt], 0, 0, 0);
      }
    }
  }

#pragma unroll
  for (int qt = 0; qt < 2; ++qt) {
    float l = l_run[qt];
    l += __shfl_xor(l, 16);
    l += __shfl_xor(l, 32);
    const float inv = 1.0f / l;
#pragma unroll
    for (int dt = 0; dt < 4; ++dt) {
      const f32x4 ov = o[dt][qt] * inv;
      *(f32x4*)(X + (size_t)(b * SS + qbase + qt * 16 + l15) * DD +
                h * DKH + dt * 16 + quad * 4) = ov;
    }
  }
}

// ---------------------------------------------------------------------------
// Epilogue: 4 rows per block (grid 1024), single barrier, wo slice in regs.
// xt = threshold(x,0.2); x1 = dot(xt,wo_sum)/1024 + bo_mean; out = xt + x1
// ---------------------------------------------------------------------------
__global__ __launch_bounds__(256) void epilogue_kernel(float* __restrict__ X,
                                                       const float* __restrict__ wo_sum,
                                                       const float* __restrict__ bo_mean) {
  __shared__ float red[4][4];
  const int tid = threadIdx.x;
  const float4 wv = *(const float4*)(wo_sum + tid * 4);
  const float bm = *bo_mean;
  float4 xt[4];
#pragma unroll
  for (int r = 0; r < 4; ++r) {
    const int row = blockIdx.x * 4 + r;
    const float4 x = *(const float4*)(X + (size_t)row * DD + tid * 4);
    xt[r].x = (x.x > 0.2f) ? x.x : 0.f;
    xt[r].y = (x.y > 0.2f) ? x.y : 0.f;
    xt[r].z = (x.z > 0.2f) ? x.z : 0.f;
    xt[r].w = (x.w > 0.2f) ? x.w : 0.f;
    float part = xt[r].x * wv.x + xt[r].y * wv.y + xt[r].z * wv.z + xt[r].w * wv.w;
#pragma unroll
    for (int off = 1; off < 64; off <<= 1) part += __shfl_xor(part, off);
    if ((tid & 63) == 0) red[r][tid >> 6] = part;
  }
  __syncthreads();
#pragma unroll
  for (int r = 0; r < 4; ++r) {
    const int row = blockIdx.x * 4 + r;
    const float x1 = ((red[r][0] + red[r][1]) + (red[r][2] + red[r][3])) * (1.0f / 1024.0f) + bm;
    const float4 o = make_float4(xt[r].x + x1, xt[r].y + x1, xt[r].z + x1, xt[r].w + x1);
    *(float4*)(X + (size_t)row * DD + tid * 4) = o;
  }
}

// ---------------------------------------------------------------------------
extern "C" void kernel_launch(void* const* d_in, const int* in_sizes, int n_in,
                              void* d_out, int out_size, void* d_ws, size_t ws_size,
                              hipStream_t stream) {
  const float* Xq = (const float*)d_in[0];
  const float* Xk = (const float*)d_in[1];
  const float* Xv = (const float*)d_in[2];
  const int* mask = (const int*)d_in[3];
  const float* Wq = (const float*)d_in[4];
  const float* bq = (const float*)d_in[5];
  const float* Wk = (const float*)d_in[6];
  const float* bk = (const float*)d_in[7];
  const float* Wv = (const float*)d_in[8];
  const float* bv = (const float*)d_in[9];
  const float* Wo = (const float*)d_in[10];
  const float* bo = (const float*)d_in[11];

  // workspace (~54 MB): Wb 6 MB + Ab 24 MB + QKVb 24 MB + tails
  ushort* Wb = (ushort*)d_ws;                     // 3 x 1048576 bf16
  ushort* Ab = Wb + (size_t)3 * 1048576;          // 3 x 4194304 bf16 (dense q,k,v)
  ushort* QKVb = Ab + (size_t)3 * 4194304;        // 3 x 4194304 bf16
  float* wo_sum = (float*)(QKVb + (size_t)3 * 4194304);
  float* bo_mean = wo_sum + 1024;
  int* maskOK = (int*)(bo_mean + 1);              // 512 ints
  float* X = (float*)d_out;

  hipMemsetAsync(wo_sum, 0, 1024 * sizeof(float), stream);

  prep_all<<<1537, 256, 0, stream>>>(Xq, Xk, Xv, mask, Wq, Wk, Wv, Wo, bo,
                                     Wb, Ab, wo_sum, bo_mean, maskOK);

  gemm_qkv_bf16<<<dim3(32, 8, 3), 256, 0, stream>>>(Ab, Wb, bq, bk, bv, QKVb);

  flash_mfma<<<dim3(16, 8, 4), 256, 0, stream>>>(QKVb, mask, maskOK, X);

  epilogue_kernel<<<1024, 256, 0, stream>>>(X, wo_sum, bo_mean);
}

// Round 10
// 219.085 us; speedup vs baseline: 1.2361x; 1.0670x over previous
//
#include <hip/hip_runtime.h>
#include <hip/hip_bf16.h>
#include <math.h>

#define BB 4
#define SS 1024
#define DD 1024
#define NH 16
#define DKH 64

typedef __attribute__((ext_vector_type(8))) short bf16x8;    // MFMA A/B frag (4 VGPRs)
typedef __attribute__((ext_vector_type(4))) float f32x4;     // 16x16 C/D frag
typedef __attribute__((ext_vector_type(16))) float f32x16;   // 32x32 C/D frag

__device__ __forceinline__ ushort f2bf(float f) {
  __hip_bfloat16 h = __float2bfloat16(f);
  return *(ushort*)&h;
}

__device__ __forceinline__ bf16x8 pack8(float4 a, float4 b) {
  bf16x8 r;
  r[0] = (short)f2bf(a.x); r[1] = (short)f2bf(a.y);
  r[2] = (short)f2bf(a.z); r[3] = (short)f2bf(a.w);
  r[4] = (short)f2bf(b.x); r[5] = (short)f2bf(b.y);
  r[6] = (short)f2bf(b.z); r[7] = (short)f2bf(b.w);
  return r;
}

// async global -> LDS, 16 B per lane; LDS dest = wave-uniform base + lane*16
__device__ __forceinline__ void async16(const void* g, void* l) {
  __builtin_amdgcn_global_load_lds(
      (const __attribute__((address_space(1))) unsigned int*)g,
      (__attribute__((address_space(3))) unsigned int*)l, 16, 0, 0);
}

// ---------------------------------------------------------------------------
// prep_all (reductions first, conversions grid-stride x8):
//  [0,64)        wo_sum: block streams 16 contiguous Wo rows, 4 atomicAdds
//  64            bo_mean (fp32, exact, deterministic)
//  [65,577)      maskOK = all-ones test per 128x64 mask tile
//  [577,1345)    q,k,v fp32 -> dense bf16 (768 blocks x 8 chunks)
//  [1345,1537)   Wq/Wk/Wv fp32 -> dense bf16 (192 blocks x 8 chunks)
// ---------------------------------------------------------------------------
__global__ __launch_bounds__(256) void prep_all(
    const float* __restrict__ Xq, const float* __restrict__ Xk, const float* __restrict__ Xv,
    const int* __restrict__ mask,
    const float* __restrict__ Wq, const float* __restrict__ Wk, const float* __restrict__ Wv,
    const float* __restrict__ Wo, const float* __restrict__ bo,
    ushort* __restrict__ Wb, ushort* __restrict__ Ab,
    float* __restrict__ wo_sum, float* __restrict__ bo_mean,
    int* __restrict__ maskOK) {
  __shared__ int smi[4];
  const int bid = blockIdx.x;
  const int tid = threadIdx.x;

  if (bid < 64) {
    const int row0 = bid * 16;
    float4 acc = make_float4(0.f, 0.f, 0.f, 0.f);
#pragma unroll
    for (int r = 0; r < 16; ++r) {
      const float4 v = *(const float4*)(Wo + (size_t)(row0 + r) * DD + tid * 4);
      acc.x += v.x; acc.y += v.y; acc.z += v.z; acc.w += v.w;
    }
    atomicAdd(&wo_sum[tid * 4 + 0], acc.x);
    atomicAdd(&wo_sum[tid * 4 + 1], acc.y);
    atomicAdd(&wo_sum[tid * 4 + 2], acc.z);
    atomicAdd(&wo_sum[tid * 4 + 3], acc.w);
    return;
  }

  if (bid == 64) {
    if (tid < 64) {
      float s = 0.f;
      for (int i = tid; i < 1024; i += 64) s += bo[i];
#pragma unroll
      for (int off = 1; off < 64; off <<= 1) s += __shfl_xor(s, off);
      if (tid == 0) *bo_mean = s * (1.0f / 1024.0f);
    }
    return;
  }

  if (bid < 577) {
    const int m = bid - 65;            // 0..511
    const int kt = m & 15, qt = (m >> 4) & 7, b = m >> 7;
    const int row = tid >> 1, half = tid & 1;
    const int* p = mask + ((size_t)b * SS + qt * 128 + row) * SS + kt * 64 + half * 32;
    int ok = 1;
#pragma unroll
    for (int j = 0; j < 8; ++j) {
      const int4 mm = *(const int4*)(p + j * 4);
      ok &= (mm.x != 0) & (mm.y != 0) & (mm.z != 0) & (mm.w != 0);
    }
    const unsigned long long bal = __ballot(ok);
    if ((tid & 63) == 0) smi[tid >> 6] = (bal == ~0ULL) ? 1 : 0;
    __syncthreads();
    if (tid == 0) maskOK[(b * 8 + qt) * 16 + kt] = smi[0] & smi[1] & smi[2] & smi[3];
    return;
  }

  if (bid < 1345) {
    const int c0 = bid - 577;          // 0..767
#pragma unroll
    for (int it = 0; it < 8; ++it) {
      const size_t g = (size_t)(c0 + it * 768) * 2048 + (size_t)tid * 8;
      const int t = (int)(g >> 22);
      const float* base = (t == 0) ? Xq : (t == 1) ? Xk : Xv;
      const size_t off = g & 4194303;
      const float4 f0 = *(const float4*)(base + off);
      const float4 f1 = *(const float4*)(base + off + 4);
      *(bf16x8*)(Ab + g) = pack8(f0, f1);
    }
    return;
  }

  {
    const int c0 = bid - 1345;         // 0..191
#pragma unroll
    for (int it = 0; it < 8; ++it) {
      const size_t g = (size_t)(c0 + it * 192) * 2048 + (size_t)tid * 8;
      const int t = (int)(g >> 20);
      const float* W = (t == 0) ? Wq : (t == 1) ? Wk : Wv;
      const size_t off = g & 1048575;
      const float4 f0 = *(const float4*)(W + off);
      const float4 f1 = *(const float4*)(W + off + 4);
      *(bf16x8*)(Wb + g) = pack8(f0, f1);
    }
  }
}

// ---------------------------------------------------------------------------
// bf16 MFMA GEMM: round-7 loop structure (BK=64, two barriers, async16 w16,
// 8-chunk XOR swizzle — measured 47 µs / 0 conflicts) upgraded to
// v_mfma_f32_32x32x16_bf16: 16 MFMA per slab instead of 32 (same FLOPs,
// same 16 ds_read_b128) -> half the matrix-pipe instruction slots and the
// 32x32 pipe's higher ceiling (2495 vs 2075 TF, m119).
// C/D mapping (verified m74/m101): m = lane&31, n = 4*(lane>>5) + (reg&3)
// + 8*(reg>>2)  (operand-swapped: W is A-operand, so D rows = C columns).
// Grid (m=32,n=8,z=3) for per-XCD A-tile L2 residency.
// ---------------------------------------------------------------------------
__global__ __launch_bounds__(256) void gemm_qkv_bf16(
    const ushort* __restrict__ Ab, const ushort* __restrict__ Wb,
    const float* __restrict__ bq, const float* __restrict__ bk, const float* __restrict__ bv,
    ushort* __restrict__ QKVb) {
  const int z = blockIdx.z;
  const char* A = (const char*)(Ab + (size_t)z * 4194304);
  const char* W = (const char*)(Wb + (size_t)z * 1048576);
  const float* bias = (z == 0) ? bq : (z == 1) ? bk : bv;
  ushort* Cz = QKVb + (size_t)z * 4194304;
  const float scale = (z == 0) ? 0.125f : 1.0f;

  __shared__ ushort As[8192];  // 128 rows x 64 elts (swizzled 8-elt chunks), 16 KB
  __shared__ ushort Ws[8192];

  const int tid = threadIdx.x;
  const int lane = tid & 63, w = tid >> 6;
  const int l31 = lane & 31, kh = lane >> 5;   // 32x32 frag coords
  const int wn = w & 1, wm = w >> 1;
  const int m0 = blockIdx.x * 128, n0 = blockIdx.y * 128;

  // staging (identical to round 7): lane L covers row grp*8 + (L>>3),
  // stored chunk L&7, global chunk (L&7) ^ (L>>3)
  const int r8 = lane >> 3;
  const int cg = (lane & 7) ^ r8;
  const int xr = l31 & 7;  // reader swizzle key (row&7)

  f32x16 acc[2][2];
#pragma unroll
  for (int mt = 0; mt < 2; ++mt)
#pragma unroll
    for (int nt = 0; nt < 2; ++nt)
#pragma unroll
      for (int r = 0; r < 16; ++r) acc[mt][nt][r] = 0.f;

  for (int k0 = 0; k0 < DD; k0 += 64) {
    __syncthreads();  // previous iteration's fragment reads done
#pragma unroll
    for (int t = 0; t < 4; ++t) {
      const int grp = w * 4 + t;          // 16 groups of 8 rows
      const int row = grp * 8 + r8;
      async16(A + ((size_t)(m0 + row) * DD + k0 + cg * 8) * 2, &As[grp * 512]);
      async16(W + ((size_t)(n0 + row) * DD + k0 + cg * 8) * 2, &Ws[grp * 512]);
    }
    __syncthreads();  // drains vmcnt: tiles visible
#pragma unroll
    for (int ks = 0; ks < 4; ++ks) {
      const int sc = (ks * 2 + kh) ^ xr;  // stored chunk for this K=16 step
      bf16x8 wf[2], af[2];
#pragma unroll
      for (int nt = 0; nt < 2; ++nt)
        wf[nt] = *(const bf16x8*)&Ws[(wn * 64 + nt * 32 + l31) * 64 + sc * 8];
#pragma unroll
      for (int mt = 0; mt < 2; ++mt)
        af[mt] = *(const bf16x8*)&As[(wm * 64 + mt * 32 + l31) * 64 + sc * 8];
#pragma unroll
      for (int mt = 0; mt < 2; ++mt)
#pragma unroll
        for (int nt = 0; nt < 2; ++nt)
          acc[mt][nt] = __builtin_amdgcn_mfma_f32_32x32x16_bf16(wf[nt], af[mt], acc[mt][nt], 0, 0, 0);
    }
  }

  // epilogue: bias + scale; reg group g holds 4 consecutive n
#pragma unroll
  for (int nt = 0; nt < 2; ++nt) {
#pragma unroll
    for (int g = 0; g < 4; ++g) {
      const int ng = n0 + wn * 64 + nt * 32 + kh * 4 + g * 8;
      const float4 b4 = *(const float4*)(bias + ng);
#pragma unroll
      for (int mt = 0; mt < 2; ++mt) {
        ushort4 pk;
        pk.x = f2bf((acc[mt][nt][g * 4 + 0] + b4.x) * scale);
        pk.y = f2bf((acc[mt][nt][g * 4 + 1] + b4.y) * scale);
        pk.z = f2bf((acc[mt][nt][g * 4 + 2] + b4.z) * scale);
        pk.w = f2bf((acc[mt][nt][g * 4 + 3] + b4.w) * scale);
        *(ushort4*)&Cz[(size_t)(m0 + wm * 64 + mt * 32 + l31) * DD + ng] = pk;
      }
    }
  }
}

// ---------------------------------------------------------------------------
// MFMA flash attention (round-7 proven kernel, unchanged): 128-q blocks,
// two-barrier LDS K-loop, K frags from global before V staging, max-free
// softmax, grid (h=16, qblk=8, b=4) for per-XCD K/V L2 residency.
// ---------------------------------------------------------------------------
__global__ __launch_bounds__(256) void flash_mfma(
    const ushort* __restrict__ QKVb, const int* __restrict__ mask,
    const int* __restrict__ maskOK, float* __restrict__ X) {
  __shared__ ushort Vt[64 * 72];   // V^T [d][key], padded
  __shared__ ushort Ps[128 * 72];  // P^T [q_local][key], padded

  const ushort* Qb = QKVb;
  const ushort* Kb = QKVb + 4194304;
  const ushort* Vb = QKVb + 8388608;

  const int tid = threadIdx.x;
  const int lane = tid & 63, w = tid >> 6;
  const int quad = lane >> 4, l15 = lane & 15;
  const int h = blockIdx.x, qblk = blockIdx.y, b = blockIdx.z;
  const int qbase = qblk * 128 + w * 32;

  bf16x8 qf[2][2];
#pragma unroll
  for (int qt = 0; qt < 2; ++qt)
#pragma unroll
    for (int ks = 0; ks < 2; ++ks)
      qf[qt][ks] = *(const bf16x8*)(Qb + (size_t)(b * SS + qbase + qt * 16 + l15) * DD +
                                    h * DKH + ks * 32 + quad * 8);

  f32x4 o[4][2];
  const f32x4 z4 = {0.f, 0.f, 0.f, 0.f};
#pragma unroll
  for (int dt = 0; dt < 4; ++dt)
#pragma unroll
    for (int qt = 0; qt < 2; ++qt) o[dt][qt] = z4;
  float l_run[2] = {0.f, 0.f};

  const int vp = tid & 31;   // key pair index
  const int vdc = tid >> 5;  // d-chunk (8 dims)
  const ushort* Vg = Vb + (size_t)(b * SS) * DD + h * DKH + vdc * 8;
  const ushort* Kg = Kb + (size_t)(b * SS) * DD + h * DKH;
  uint* VtU = (uint*)Vt;
  const int* Mb = mask + (size_t)b * SS * SS;

  for (int kt = 0; kt < 16; ++kt) {
    const int k064 = kt * 64;
    __syncthreads();  // prior iteration's Vt/Ps reads complete

    bf16x8 kf[4][2];
#pragma unroll
    for (int mt = 0; mt < 4; ++mt)
#pragma unroll
      for (int ks = 0; ks < 2; ++ks)
        kf[mt][ks] = *(const bf16x8*)(Kg + (size_t)(k064 + mt * 16 + l15) * DD +
                                      ks * 32 + quad * 8);

    union { uint4 u; ushort s[8]; } v0, v1;
    v0.u = *(const uint4*)(Vg + (size_t)(k064 + 2 * vp) * DD);
    v1.u = *(const uint4*)(Vg + (size_t)(k064 + 2 * vp + 1) * DD);
#pragma unroll
    for (int j = 0; j < 8; ++j)
      VtU[(vdc * 8 + j) * 36 + vp] = (uint)v0.s[j] | ((uint)v1.s[j] << 16);
    __syncthreads();  // Vt visible

    f32x4 s[4][2];
#pragma unroll
    for (int mt = 0; mt < 4; ++mt)
#pragma unroll
      for (int qt = 0; qt < 2; ++qt) {
        f32x4 a = z4;
        a = __builtin_amdgcn_mfma_f32_16x16x32_bf16(kf[mt][0], qf[qt][0], a, 0, 0, 0);
        a = __builtin_amdgcn_mfma_f32_16x16x32_bf16(kf[mt][1], qf[qt][1], a, 0, 0, 0);
        s[mt][qt] = a;
      }

    const int ok = maskOK[(b * 8 + qblk) * 16 + kt];
    if (!ok) {
#pragma unroll
      for (int mt = 0; mt < 4; ++mt)
#pragma unroll
        for (int qt = 0; qt < 2; ++qt)
#pragma unroll
          for (int reg = 0; reg < 4; ++reg) {
            const int q = qbase + qt * 16 + l15;
            const int key = k064 + mt * 16 + quad * 4 + reg;
            if (Mb[(size_t)q * SS + key] == 0) s[mt][qt][reg] = -1e9f;
          }
    }

#pragma unroll
    for (int qt = 0; qt < 2; ++qt) {
      float rs = 0.f;
#pragma unroll
      for (int mt = 0; mt < 4; ++mt) {
#pragma unroll
        for (int reg = 0; reg < 4; ++reg) {
          const float p = __expf(s[mt][qt][reg]);
          s[mt][qt][reg] = p;
          rs += p;
        }
      }
      l_run[qt] += rs;
#pragma unroll
      for (int mt = 0; mt < 4; ++mt) {
        ushort4 pk;
        pk.x = f2bf(s[mt][qt][0]);
        pk.y = f2bf(s[mt][qt][1]);
        pk.z = f2bf(s[mt][qt][2]);
        pk.w = f2bf(s[mt][qt][3]);
        *(ushort4*)&Ps[(w * 32 + qt * 16 + l15) * 72 + mt * 16 + quad * 4] = pk;
      }
    }

    bf16x8 pf[2][2];
#pragma unroll
    for (int qt = 0; qt < 2; ++qt)
#pragma unroll
      for (int ks = 0; ks < 2; ++ks)
        pf[qt][ks] = *(const bf16x8*)&Ps[(w * 32 + qt * 16 + l15) * 72 + ks * 32 + quad * 8];
#pragma unroll
    for (int dt = 0; dt < 4; ++dt) {
      bf16x8 vf0 = *(const bf16x8*)&Vt[(dt * 16 + l15) * 72 + quad * 8];
      bf16x8 vf1 = *(const bf16x8*)&Vt[(dt * 16 + l15) * 72 + 32 + quad * 8];
#pragma unroll
      for (int qt = 0; qt < 2; ++qt) {
        o[dt][qt] = __builtin_amdgcn_mfma_f32_16x16x32_bf16(vf0, pf[qt][0], o[dt][qt], 0, 0, 0);
        o[dt][qt] = __builtin_amdgcn_mfma_f32_16x16x32_bf16(vf1, pf[qt][1], o[dt][qt], 0, 0, 0);
      }
    }
  }

#pragma unroll
  for (int qt = 0; qt < 2; ++qt) {
    float l = l_run[qt];
    l += __shfl_xor(l, 16);
    l += __shfl_xor(l, 32);
    const float inv = 1.0f / l;
#pragma unroll
    for (int dt = 0; dt < 4; ++dt) {
      const f32x4 ov = o[dt][qt] * inv;
      *(f32x4*)(X + (size_t)(b * SS + qbase + qt * 16 + l15) * DD +
                h * DKH + dt * 16 + quad * 4) = ov;
    }
  }
}

// ---------------------------------------------------------------------------
// Epilogue: 4 rows per block (grid 1024), single barrier, wo slice in regs.
// xt = threshold(x,0.2); x1 = dot(xt,wo_sum)/1024 + bo_mean; out = xt + x1
// ---------------------------------------------------------------------------
__global__ __launch_bounds__(256) void epilogue_kernel(float* __restrict__ X,
                                                       const float* __restrict__ wo_sum,
                                                       const float* __restrict__ bo_mean) {
  __shared__ float red[4][4];
  const int tid = threadIdx.x;
  const float4 wv = *(const float4*)(wo_sum + tid * 4);
  const float bm = *bo_mean;
  float4 xt[4];
#pragma unroll
  for (int r = 0; r < 4; ++r) {
    const int row = blockIdx.x * 4 + r;
    const float4 x = *(const float4*)(X + (size_t)row * DD + tid * 4);
    xt[r].x = (x.x > 0.2f) ? x.x : 0.f;
    xt[r].y = (x.y > 0.2f) ? x.y : 0.f;
    xt[r].z = (x.z > 0.2f) ? x.z : 0.f;
    xt[r].w = (x.w > 0.2f) ? x.w : 0.f;
    float part = xt[r].x * wv.x + xt[r].y * wv.y + xt[r].z * wv.z + xt[r].w * wv.w;
#pragma unroll
    for (int off = 1; off < 64; off <<= 1) part += __shfl_xor(part, off);
    if ((tid & 63) == 0) red[r][tid >> 6] = part;
  }
  __syncthreads();
#pragma unroll
  for (int r = 0; r < 4; ++r) {
    const int row = blockIdx.x * 4 + r;
    const float x1 = ((red[r][0] + red[r][1]) + (red[r][2] + red[r][3])) * (1.0f / 1024.0f) + bm;
    const float4 o = make_float4(xt[r].x + x1, xt[r].y + x1, xt[r].z + x1, xt[r].w + x1);
    *(float4*)(X + (size_t)row * DD + tid * 4) = o;
  }
}

// ---------------------------------------------------------------------------
extern "C" void kernel_launch(void* const* d_in, const int* in_sizes, int n_in,
                              void* d_out, int out_size, void* d_ws, size_t ws_size,
                              hipStream_t stream) {
  const float* Xq = (const float*)d_in[0];
  const float* Xk = (const float*)d_in[1];
  const float* Xv = (const float*)d_in[2];
  const int* mask = (const int*)d_in[3];
  const float* Wq = (const float*)d_in[4];
  const float* bq = (const float*)d_in[5];
  const float* Wk = (const float*)d_in[6];
  const float* bk = (const float*)d_in[7];
  const float* Wv = (const float*)d_in[8];
  const float* bv = (const float*)d_in[9];
  const float* Wo = (const float*)d_in[10];
  const float* bo = (const float*)d_in[11];

  // workspace (~54 MB): Wb 6 MB + Ab 24 MB + QKVb 24 MB + tails
  ushort* Wb = (ushort*)d_ws;                     // 3 x 1048576 bf16
  ushort* Ab = Wb + (size_t)3 * 1048576;          // 3 x 4194304 bf16 (dense q,k,v)
  ushort* QKVb = Ab + (size_t)3 * 4194304;        // 3 x 4194304 bf16
  float* wo_sum = (float*)(QKVb + (size_t)3 * 4194304);
  float* bo_mean = wo_sum + 1024;
  int* maskOK = (int*)(bo_mean + 1);              // 512 ints
  float* X = (float*)d_out;

  hipMemsetAsync(wo_sum, 0, 1024 * sizeof(float), stream);

  prep_all<<<1537, 256, 0, stream>>>(Xq, Xk, Xv, mask, Wq, Wk, Wv, Wo, bo,
                                     Wb, Ab, wo_sum, bo_mean, maskOK);

  gemm_qkv_bf16<<<dim3(32, 8, 3), 256, 0, stream>>>(Ab, Wb, bq, bk, bv, QKVb);

  flash_mfma<<<dim3(16, 8, 4), 256, 0, stream>>>(QKVb, mask, maskOK, X);

  epilogue_kernel<<<1024, 256, 0, stream>>>(X, wo_sum, bo_mean);
}